// Round 7
// baseline (264.867 us; speedup 1.0000x reference)
//
#include <hip/hip_runtime.h>
#include <math.h>

// ---------------- problem constants ----------------
constexpr int N_A   = 16384;
constexpr int N_P   = 16384;
constexpr int IN_D  = 128;
constexpr int HID   = 64;
constexpr int NH    = 4;    // heads
constexpr int OUTD  = 349;
constexpr int NE    = 262144; // edges per type (2^18)
constexpr float NEG = 0.2f;

__device__ __forceinline__ float lrelu(float x) { return x > 0.f ? x : NEG * x; }

// ---------------- CSR build (once per call; edge lists shared by both layers)
__global__ __launch_bounds__(256) void k_zero(int* __restrict__ cnt) {
    int i = blockIdx.x * 256 + threadIdx.x;
    if (i < 3 * 16384) cnt[i] = 0;
}

__global__ __launch_bounds__(256) void k_hist(const int* __restrict__ dW, const int* __restrict__ dC,
                                              const int* __restrict__ dR, int* __restrict__ cnt) {
    int idx = blockIdx.x * 256 + threadIdx.x;   // 3*NE
    int t = idx >> 18, i = idx & (NE - 1);
    const int* d = t == 0 ? dW : t == 1 ? dC : dR;
    atomicAdd(cnt + t * 16384 + d[i], 1);
}

__global__ __launch_bounds__(1024) void k_scan(const int* __restrict__ cnt, int* __restrict__ row,
                                               int* __restrict__ cur) {
    int b = blockIdx.x;                          // type
    const int* c = cnt + b * 16384;
    int* r = row + b * 16385;
    int* q = cur + b * 16384;
    __shared__ int part[1024];
    int t = threadIdx.x;
    int loc[16], s = 0;
#pragma unroll
    for (int i = 0; i < 16; ++i) { loc[i] = s; s += c[t * 16 + i]; }
    part[t] = s;
    __syncthreads();
    for (int w = 1; w < 1024; w <<= 1) {
        int v = (t >= w) ? part[t - w] : 0;
        __syncthreads();
        part[t] += v;
        __syncthreads();
    }
    int off = (t > 0) ? part[t - 1] : 0;
#pragma unroll
    for (int i = 0; i < 16; ++i) {
        int v = off + loc[i];
        r[t * 16 + i] = v;
        q[t * 16 + i] = v;
    }
    if (t == 1023) r[16384] = part[1023];
}

__global__ __launch_bounds__(256) void k_scatter(const int* __restrict__ sW, const int* __restrict__ dW,
                                                 const int* __restrict__ sC, const int* __restrict__ dC,
                                                 const int* __restrict__ sR, const int* __restrict__ dR,
                                                 int* __restrict__ cur,
                                                 int* __restrict__ eW, int* __restrict__ eC,
                                                 int* __restrict__ eR) {
    int idx = blockIdx.x * 256 + threadIdx.x;   // 3*NE
    int t = idx >> 18, i = idx & (NE - 1);
    const int* sp = t == 0 ? sW : t == 1 ? sC : sR;
    const int* dp = t == 0 ? dW : t == 1 ? dC : dR;
    int* ep = t == 0 ? eW : t == 1 ? eC : eR;
    int pos = atomicAdd(cur + t * 16384 + dp[i], 1);
    ep[pos] = sp[i];
}

// ---------------- batched GEMM (X@W) + el/er head reductions -------
// 4x4 register tile per thread (rows rg*4+i, cols tx*4+q); X staged
// TRANSPOSED (XT[k][row], pad 68 keeps b128 reads aligned+conflict-free);
// W staged in 32-k chunks. Per kk: 2x ds_read_b128 for 16 FMAs.
struct GemmJobs {
    const float* X[5];  const float* W[5];  const float* NT[5];
    float* F[5];        float* EL[5];       float* ER[5];
    const float* AL[5]; const float* AR[5];
};

template <int K, int RELU>
__global__ __launch_bounds__(256) void k_gemm(GemmJobs j) {
    __shared__ float Wc[32 * 64];
    __shared__ float XT[32][68];

    const float* __restrict__ X;  const float* __restrict__ Wp;  const float* __restrict__ NTp;
    float* __restrict__ F;  float* __restrict__ EL;  float* __restrict__ ER;
    const float* __restrict__ AL; const float* __restrict__ AR;
    switch (blockIdx.z) {                         // block-uniform, static indices
      case 0: X=j.X[0]; Wp=j.W[0]; NTp=j.NT[0]; F=j.F[0]; EL=j.EL[0]; ER=j.ER[0]; AL=j.AL[0]; AR=j.AR[0]; break;
      case 1: X=j.X[1]; Wp=j.W[1]; NTp=j.NT[1]; F=j.F[1]; EL=j.EL[1]; ER=j.ER[1]; AL=j.AL[1]; AR=j.AR[1]; break;
      case 2: X=j.X[2]; Wp=j.W[2]; NTp=j.NT[2]; F=j.F[2]; EL=j.EL[2]; ER=j.ER[2]; AL=j.AL[2]; AR=j.AR[2]; break;
      case 3: X=j.X[3]; Wp=j.W[3]; NTp=j.NT[3]; F=j.F[3]; EL=j.EL[3]; ER=j.ER[3]; AL=j.AL[3]; AR=j.AR[3]; break;
      default: X=j.X[4]; Wp=j.W[4]; NTp=j.NT[4]; F=j.F[4]; EL=j.EL[4]; ER=j.ER[4]; AL=j.AL[4]; AR=j.AR[4]; break;
    }

    const int tid = threadIdx.x;
    const int tx  = tid & 15;     // col group: cols tx*4..tx*4+3
    const int rg  = tid >> 4;     // row group: rows rg*4..rg*4+3
    const int r0  = blockIdx.x * 64;

    float acc[4][4] = {};

    for (int kc = 0; kc < K; kc += 32) {
        __syncthreads();
        // stage W chunk (32x64)
#pragma unroll
        for (int it = 0; it < 2; ++it) {
            int idx = tid * 4 + it * 1024;
            int k = idx >> 6, c = idx & 63;
            *(float4*)(Wc + idx) = *(const float4*)(Wp + (size_t)(kc + k) * 64 + c);
        }
        // stage X chunk transposed (XT[k][row])
#pragma unroll
        for (int it = 0; it < 2; ++it) {
            int idx = tid * 4 + it * 1024;
            int row = idx >> 5, col = idx & 31;
            float4 v = *(const float4*)(X + (size_t)(r0 + row) * K + kc + col);
            if (RELU) {
                v.x = fmaxf(v.x, 0.f); v.y = fmaxf(v.y, 0.f);
                v.z = fmaxf(v.z, 0.f); v.w = fmaxf(v.w, 0.f);
            }
            if (NTp) {
                float4 s = *(const float4*)(NTp + kc + col);
                v.x *= s.x; v.y *= s.y; v.z *= s.z; v.w *= s.w;
            }
            XT[col + 0][row] = v.x;
            XT[col + 1][row] = v.y;
            XT[col + 2][row] = v.z;
            XT[col + 3][row] = v.w;
        }
        __syncthreads();
#pragma unroll
        for (int kk = 0; kk < 32; ++kk) {
            float4 a4 = *(const float4*)(&XT[kk][rg * 4]);
            float4 w4 = *(const float4*)(Wc + kk * 64 + tx * 4);
            acc[0][0] = fmaf(a4.x, w4.x, acc[0][0]); acc[0][1] = fmaf(a4.x, w4.y, acc[0][1]);
            acc[0][2] = fmaf(a4.x, w4.z, acc[0][2]); acc[0][3] = fmaf(a4.x, w4.w, acc[0][3]);
            acc[1][0] = fmaf(a4.y, w4.x, acc[1][0]); acc[1][1] = fmaf(a4.y, w4.y, acc[1][1]);
            acc[1][2] = fmaf(a4.y, w4.z, acc[1][2]); acc[1][3] = fmaf(a4.y, w4.w, acc[1][3]);
            acc[2][0] = fmaf(a4.z, w4.x, acc[2][0]); acc[2][1] = fmaf(a4.z, w4.y, acc[2][1]);
            acc[2][2] = fmaf(a4.z, w4.z, acc[2][2]); acc[2][3] = fmaf(a4.z, w4.w, acc[2][3]);
            acc[3][0] = fmaf(a4.w, w4.x, acc[3][0]); acc[3][1] = fmaf(a4.w, w4.y, acc[3][1]);
            acc[3][2] = fmaf(a4.w, w4.z, acc[3][2]); acc[3][3] = fmaf(a4.w, w4.w, acc[3][3]);
        }
    }

    if (F) {
#pragma unroll
        for (int i = 0; i < 4; ++i) {
            size_t n = (size_t)r0 + rg * 4 + i;
            *(float4*)(F + n * 64 + tx * 4) =
                make_float4(acc[i][0], acc[i][1], acc[i][2], acc[i][3]);
        }
    }
    // el/er: thread's 4 cols belong to head tx>>2; reduce over the 4 lanes of
    // the head group (lane bits 0,1) via shfl_xor.
    if (EL) {
        float4 alv = ((const float4*)AL)[tx];
#pragma unroll
        for (int i = 0; i < 4; ++i) {
            float p = acc[i][0] * alv.x + acc[i][1] * alv.y +
                      acc[i][2] * alv.z + acc[i][3] * alv.w;
            p += __shfl_xor(p, 1, 64);
            p += __shfl_xor(p, 2, 64);
            if ((tx & 3) == 0) EL[((size_t)r0 + rg * 4 + i) * 4 + (tx >> 2)] = p;
        }
    }
    if (ER) {
        float4 arv = ((const float4*)AR)[tx];
#pragma unroll
        for (int i = 0; i < 4; ++i) {
            float p = acc[i][0] * arv.x + acc[i][1] * arv.y +
                      acc[i][2] * arv.z + acc[i][3] * arv.w;
            p += __shfl_xor(p, 1, 64);
            p += __shfl_xor(p, 2, 64);
            if ((tx & 3) == 0) ER[((size_t)r0 + rg * 4 + i) * 4 + (tx >> 2)] = p;
        }
    }
}

// ---------------- per-destination gather aggregation (no atomics) ----------
// SINGLE-PASS: softmax is shift-invariant and scores here are bounded
// (|e| <~ 6 << 88), so the segment-max pass is dropped: w=exp(e), den and the
// unnormalized feature sum accumulate together, one normalize at the end.
// (Two-pass max version measured 47.7us: latency-chain bound, VALU 37%.)
struct AggType { const int* row; const int* es; const float* el; const float* er; const float* fs; };
struct AggArgs { AggType t[3]; const float* b; float* op; float* oa; };

__device__ __forceinline__ float agg16(const int* __restrict__ rowv, const int* __restrict__ es,
                                       const float* __restrict__ el, const float* __restrict__ er,
                                       const float* __restrict__ fs, int d, int lane) {
    int start = rowv[d], end = rowv[d + 1];
    int deg = end - start;
    if (deg <= 0) return 0.f;
    const int g = lane >> 4, j16 = lane & 15;
    const float rh = er[(size_t)d * 4 + g];

    float den = 0.f, acc = 0.f;
    for (int e0 = 0; e0 < deg; e0 += 16) {
        int o = e0 + j16;
        int sn = es[start + (o < deg ? o : 0)];
        float wv = 0.f;
        if (o < deg) wv = __expf(lrelu(el[(size_t)sn * 4 + g] + rh));
        den += wv;
#pragma unroll
        for (int jj = 0; jj < 16; ++jj) {
            if (e0 + jj >= deg) break;                       // wave-uniform
            int snj = __shfl(sn, jj, 64);                    // edge jj's src
            float wj = __shfl(wv, (lane & 48) + jj, 64);     // head-specific weight
            acc = fmaf(wj, fs[(size_t)snj * 64 + lane], acc);
        }
    }
#pragma unroll
    for (int w = 1; w < 16; w <<= 1) den += __shfl_xor(den, w, 64);
    return acc * (1.f / fmaxf(den, 1e-9f));
}

__global__ __launch_bounds__(256) void k_agg(AggArgs A) {
    int wid = (blockIdx.x * 256 + threadIdx.x) >> 6;  // one wave per dst node
    int lane = threadIdx.x & 63;
    if (wid < N_P) {
        // paper node: writes-GAT + cites-GAT (+ both biases)
        float acc = A.b[lane] + A.b[64 + lane];
        acc += agg16(A.t[0].row, A.t[0].es, A.t[0].el, A.t[0].er, A.t[0].fs, wid, lane);
        acc += agg16(A.t[1].row, A.t[1].es, A.t[1].el, A.t[1].er, A.t[1].fs, wid, lane);
        A.op[(size_t)wid * 64 + lane] = acc;
    } else {
        int d = wid - N_P;
        float acc = A.b[128 + lane];
        acc += agg16(A.t[2].row, A.t[2].es, A.t[2].el, A.t[2].er, A.t[2].fs, d, lane);
        A.oa[(size_t)d * 64 + lane] = acc;
    }
}

// ---------------- hf build: h2 = h1 + C, row l2-normalize, concat ------------
__global__ __launch_bounds__(256) void k_hf(const float* __restrict__ h1, float* __restrict__ hf,
                                            const float* __restrict__ ln1gb,
                                            const float* __restrict__ aw, const float* __restrict__ ab,
                                            const float* __restrict__ ln2gb,
                                            const float* __restrict__ fw1, const float* __restrict__ fb1,
                                            const float* __restrict__ fw2, const float* __restrict__ fb2) {
    __shared__ float Cs;
    if (threadIdx.x == 0) {
        // LN over size-1 axis -> exactly its bias term
        float y1 = ln1gb[1];
        float v  = y1 * aw[2] + ab[2];          // v constant; softmax uniform -> o = v
        float o  = v * aw[3] + ab[3];
        float y2 = ln2gb[1];
        float f  = fb2[0];
#pragma unroll
        for (int q = 0; q < 16; ++q) {
            float zz = y2 * fw1[q] + fb1[q];
            f += 0.5f * zz * (1.f + erff(zz * 0.70710678118654752f)) * fw2[q];
        }
        Cs = o + f;
    }
    __syncthreads();
    float C = Cs;
    int lane = threadIdx.x & 63;
    int row  = blockIdx.x * 4 + (threadIdx.x >> 6);
    float v1 = h1[(size_t)row * 64 + lane];
    float s1 = v1 * v1;
#pragma unroll
    for (int w = 1; w < 64; w <<= 1) s1 += __shfl_xor(s1, w, 64);
    float o1 = v1 / fmaxf(sqrtf(s1), 1e-12f);
    float v2 = v1 + C;
    float s2 = v2 * v2;
#pragma unroll
    for (int w = 1; w < 64; w <<= 1) s2 += __shfl_xor(s2, w, 64);
    float o2 = v2 / fmaxf(sqrtf(s2), 1e-12f);
    hf[(size_t)row * 128 + lane]      = o1;
    hf[(size_t)row * 128 + 64 + lane] = o2;
}

// ---------------- final GEMM: out = hf(16384x128) @ linW(128x349) + linb -----
// Same 4x4 register-tile structure as k_gemm (W chunked, XT transposed).
__global__ __launch_bounds__(256) void k_gemm_out(const float* __restrict__ X,
                                                  const float* __restrict__ W,
                                                  const float* __restrict__ bias,
                                                  float* __restrict__ out) {
    __shared__ float Wc[32 * 64];
    __shared__ float XT[32][68];
    const int tid = threadIdx.x;
    const int tx  = tid & 15;
    const int rg  = tid >> 4;
    const int r0  = blockIdx.x * 64;
    const int c0  = blockIdx.y * 64;

    float acc[4][4] = {};

    for (int kc = 0; kc < 128; kc += 32) {
        __syncthreads();
#pragma unroll
        for (int it = 0; it < 2; ++it) {
            int idx = tid * 4 + it * 1024;
            int k = idx >> 6, c = idx & 63;
            int gk = kc + k;
            float4 v;
            int gc = c0 + c;
            v.x = (gc + 0 < OUTD) ? W[(size_t)gk * OUTD + gc + 0] : 0.f;
            v.y = (gc + 1 < OUTD) ? W[(size_t)gk * OUTD + gc + 1] : 0.f;
            v.z = (gc + 2 < OUTD) ? W[(size_t)gk * OUTD + gc + 2] : 0.f;
            v.w = (gc + 3 < OUTD) ? W[(size_t)gk * OUTD + gc + 3] : 0.f;
            *(float4*)(Wc + idx) = v;
        }
#pragma unroll
        for (int it = 0; it < 2; ++it) {
            int idx = tid * 4 + it * 1024;
            int row = idx >> 5, col = idx & 31;
            float4 v = *(const float4*)(X + (size_t)(r0 + row) * 128 + kc + col);
            XT[col + 0][row] = v.x;
            XT[col + 1][row] = v.y;
            XT[col + 2][row] = v.z;
            XT[col + 3][row] = v.w;
        }
        __syncthreads();
#pragma unroll
        for (int kk = 0; kk < 32; ++kk) {
            float4 a4 = *(const float4*)(&XT[kk][rg * 4]);
            float4 w4 = *(const float4*)(Wc + kk * 64 + tx * 4);
            acc[0][0] = fmaf(a4.x, w4.x, acc[0][0]); acc[0][1] = fmaf(a4.x, w4.y, acc[0][1]);
            acc[0][2] = fmaf(a4.x, w4.z, acc[0][2]); acc[0][3] = fmaf(a4.x, w4.w, acc[0][3]);
            acc[1][0] = fmaf(a4.y, w4.x, acc[1][0]); acc[1][1] = fmaf(a4.y, w4.y, acc[1][1]);
            acc[1][2] = fmaf(a4.y, w4.z, acc[1][2]); acc[1][3] = fmaf(a4.y, w4.w, acc[1][3]);
            acc[2][0] = fmaf(a4.z, w4.x, acc[2][0]); acc[2][1] = fmaf(a4.z, w4.y, acc[2][1]);
            acc[2][2] = fmaf(a4.z, w4.z, acc[2][2]); acc[2][3] = fmaf(a4.z, w4.w, acc[2][3]);
            acc[3][0] = fmaf(a4.w, w4.x, acc[3][0]); acc[3][1] = fmaf(a4.w, w4.y, acc[3][1]);
            acc[3][2] = fmaf(a4.w, w4.z, acc[3][2]); acc[3][3] = fmaf(a4.w, w4.w, acc[3][3]);
        }
    }

    float b4[4];
#pragma unroll
    for (int q = 0; q < 4; ++q) {
        int c = c0 + tx * 4 + q;
        b4[q] = (c < OUTD) ? bias[c] : 0.f;
    }
#pragma unroll
    for (int i = 0; i < 4; ++i) {
        size_t n = (size_t)r0 + rg * 4 + i;
#pragma unroll
        for (int q = 0; q < 4; ++q) {
            int c = c0 + tx * 4 + q;
            if (c < OUTD) out[n * OUTD + c] = acc[i][q] + b4[q];
        }
    }
}

// ---------------- host ----------------
extern "C" void kernel_launch(void* const* d_in, const int* in_sizes, int n_in,
                              void* d_out, int out_size, void* d_ws, size_t ws_size,
                              hipStream_t stream) {
    const float* x_author = (const float*)d_in[0];
    const float* x_paper  = (const float*)d_in[1];
    const float* ntype    = (const float*)d_in[2];
    const float* W0  = (const float*)d_in[3];
    const float* al0 = (const float*)d_in[4];
    const float* ar0 = (const float*)d_in[5];
    const float* b0  = (const float*)d_in[6];
    const float* W1  = (const float*)d_in[7];
    const float* al1 = (const float*)d_in[8];
    const float* ar1 = (const float*)d_in[9];
    const float* b1  = (const float*)d_in[10];
    const float* ln1gb = (const float*)d_in[11];
    const float* attw  = (const float*)d_in[12];
    const float* attb  = (const float*)d_in[13];
    const float* ln2gb = (const float*)d_in[14];
    const float* fw1 = (const float*)d_in[15];
    const float* fb1 = (const float*)d_in[16];
    const float* fw2 = (const float*)d_in[17];
    const float* fb2 = (const float*)d_in[18];
    const float* linW = (const float*)d_in[19];
    const float* linb = (const float*)d_in[20];
    const int* srcW = (const int*)d_in[21];
    const int* dstW = (const int*)d_in[22];
    const int* srcC = (const int*)d_in[23];
    const int* dstC = (const int*)d_in[24];
    const int* srcR = (const int*)d_in[25];
    const int* dstR = (const int*)d_in[26];
    float* out = (float*)d_out;

    // ---- workspace carve-up ----
    float* ws = (float*)d_ws;
    size_t off = 0;
    float* fsW = ws + off; off += (size_t)N_A * HID;
    float* fsC = ws + off; off += (size_t)N_P * HID;
    float* fsR = ws + off; off += (size_t)N_P * HID;
    float* elw = ws + off; off += (size_t)N_A * NH;
    float* erw = ws + off; off += (size_t)N_P * NH;
    float* elc = ws + off; off += (size_t)N_P * NH;
    float* erc = ws + off; off += (size_t)N_P * NH;
    float* elr = ws + off; off += (size_t)N_P * NH;
    float* err = ws + off; off += (size_t)N_A * NH;
    float* oa0 = ws + off; off += (size_t)N_A * HID;
    float* op0 = ws + off; off += (size_t)N_P * HID;
    float* oa1 = ws + off; off += (size_t)N_A * HID;
    float* op1 = ws + off; off += (size_t)N_P * HID;
    float* hf  = ws + off; off += (size_t)N_P * 2 * HID;
    int* cnt  = (int*)(ws + off); off += 3 * 16384;
    int* row  = (int*)(ws + off); off += 3 * 16385 + 1;   // +1 keeps alignment slack
    int* cur  = (int*)(ws + off); off += 3 * 16384;
    int* esW  = (int*)(ws + off); off += NE;
    int* esC  = (int*)(ws + off); off += NE;
    int* esR  = (int*)(ws + off); off += NE;

    const int* rowW = row;
    const int* rowC = row + 16385;
    const int* rowR = row + 2 * 16385;

    const float* ntA = ntype;            // author scale row (128)
    const float* ntP = ntype + IN_D;     // paper scale row

    // ---- layer job tables (layer 0 reads raw x, scaled by NT on load) ----
    GemmJobs j0{};
    j0.X[0] = x_author; j0.W[0] = W0;                  j0.NT[0] = ntA;
    j0.F[0] = fsW; j0.EL[0] = elw; j0.ER[0] = nullptr; j0.AL[0] = al0;       j0.AR[0] = nullptr;
    j0.X[1] = x_paper;  j0.W[1] = W0;                  j0.NT[1] = ntP;
    j0.F[1] = nullptr; j0.EL[1] = nullptr; j0.ER[1] = erw; j0.AL[1] = nullptr; j0.AR[1] = ar0;
    j0.X[2] = x_paper;  j0.W[2] = W0 + IN_D * HID;     j0.NT[2] = ntP;
    j0.F[2] = fsC; j0.EL[2] = elc; j0.ER[2] = erc;     j0.AL[2] = al0 + 64;  j0.AR[2] = ar0 + 64;
    j0.X[3] = x_paper;  j0.W[3] = W0 + 2 * IN_D * HID; j0.NT[3] = ntP;
    j0.F[3] = fsR; j0.EL[3] = elr; j0.ER[3] = nullptr; j0.AL[3] = al0 + 128; j0.AR[3] = nullptr;
    j0.X[4] = x_author; j0.W[4] = W0 + 2 * IN_D * HID; j0.NT[4] = ntA;
    j0.F[4] = nullptr; j0.EL[4] = nullptr; j0.ER[4] = err; j0.AL[4] = nullptr; j0.AR[4] = ar0 + 128;

    GemmJobs j1{};
    j1.X[0] = oa0; j1.W[0] = W1;                   j1.NT[0] = nullptr;
    j1.F[0] = fsW; j1.EL[0] = elw; j1.ER[0] = nullptr; j1.AL[0] = al1;       j1.AR[0] = nullptr;
    j1.X[1] = op0; j1.W[1] = W1;                   j1.NT[1] = nullptr;
    j1.F[1] = nullptr; j1.EL[1] = nullptr; j1.ER[1] = erw; j1.AL[1] = nullptr; j1.AR[1] = ar1;
    j1.X[2] = op0; j1.W[2] = W1 + HID * HID;       j1.NT[2] = nullptr;
    j1.F[2] = fsC; j1.EL[2] = elc; j1.ER[2] = erc;     j1.AL[2] = al1 + 64;  j1.AR[2] = ar1 + 64;
    j1.X[3] = op0; j1.W[3] = W1 + 2 * HID * HID;   j1.NT[3] = nullptr;
    j1.F[3] = fsR; j1.EL[3] = elr; j1.ER[3] = nullptr; j1.AL[3] = al1 + 128; j1.AR[3] = nullptr;
    j1.X[4] = oa0; j1.W[4] = W1 + 2 * HID * HID;   j1.NT[4] = nullptr;
    j1.F[4] = nullptr; j1.EL[4] = nullptr; j1.ER[4] = err; j1.AL[4] = nullptr; j1.AR[4] = ar1 + 128;

    AggArgs a0{};
    a0.t[0] = {rowW, esW, elw, erw, fsW};
    a0.t[1] = {rowC, esC, elc, erc, fsC};
    a0.t[2] = {rowR, esR, elr, err, fsR};
    a0.b = b0; a0.op = op0; a0.oa = oa0;
    AggArgs a1 = a0;
    a1.b = b1; a1.op = op1; a1.oa = oa1;

    // ---- launches ----
    // CSR build (edge lists constant across layers)
    k_zero<<<(3 * 16384 + 255) / 256, 256, 0, stream>>>(cnt);
    k_hist<<<3 * NE / 256, 256, 0, stream>>>(dstW, dstC, dstR, cnt);
    k_scan<<<3, 1024, 0, stream>>>(cnt, row, cur);
    k_scatter<<<3 * NE / 256, 256, 0, stream>>>(srcW, dstW, srcC, dstC, srcR, dstR, cur, esW, esC, esR);

    // layer 0 (ntype scale folded into X load)
    k_gemm<IN_D, 0><<<dim3(N_A / 64, 1, 5), 256, 0, stream>>>(j0);
    k_agg<<<(N_P + N_A) / 4, 256, 0, stream>>>(a0);

    // layer 1 (relu folded into GEMM X loads)
    k_gemm<HID, 1><<<dim3(N_A / 64, 1, 5), 256, 0, stream>>>(j1);
    k_agg<<<(N_P + N_A) / 4, 256, 0, stream>>>(a1);

    // epilogue
    k_hf<<<N_P / 4, 256, 0, stream>>>(op1, hf, ln1gb, attw, attb, ln2gb, fw1, fb1, fw2, fb2);
    k_gemm_out<<<dim3(N_P / 64, (OUTD + 63) / 64), 256, 0, stream>>>(hf, linW, linb, out);
}

// Round 8
// 225.510 us; speedup vs baseline: 1.1745x; 1.1745x over previous
//
#include <hip/hip_runtime.h>
#include <math.h>

// ---------------- problem constants ----------------
constexpr int N_A   = 16384;
constexpr int N_P   = 16384;
constexpr int IN_D  = 128;
constexpr int HID   = 64;
constexpr int NH    = 4;    // heads
constexpr int OUTD  = 349;
constexpr int NE    = 262144; // edges per type (2^18)
constexpr float NEG = 0.2f;

__device__ __forceinline__ float lrelu(float x) { return x > 0.f ? x : NEG * x; }

// ---------------- CSR build (once per call; edge lists shared by both layers)
__global__ __launch_bounds__(256) void k_zero(int* __restrict__ cnt) {
    int i = blockIdx.x * 256 + threadIdx.x;
    if (i < 3 * 16384) cnt[i] = 0;
}

__global__ __launch_bounds__(256) void k_hist(const int* __restrict__ dW, const int* __restrict__ dC,
                                              const int* __restrict__ dR, int* __restrict__ cnt) {
    int idx = blockIdx.x * 256 + threadIdx.x;   // 3*NE
    int t = idx >> 18, i = idx & (NE - 1);
    const int* d = t == 0 ? dW : t == 1 ? dC : dR;
    atomicAdd(cnt + t * 16384 + d[i], 1);
}

__global__ __launch_bounds__(1024) void k_scan(const int* __restrict__ cnt, int* __restrict__ row,
                                               int* __restrict__ cur) {
    int b = blockIdx.x;                          // type
    const int* c = cnt + b * 16384;
    int* r = row + b * 16385;
    int* q = cur + b * 16384;
    __shared__ int part[1024];
    int t = threadIdx.x;
    int loc[16], s = 0;
#pragma unroll
    for (int i = 0; i < 16; ++i) { loc[i] = s; s += c[t * 16 + i]; }
    part[t] = s;
    __syncthreads();
    for (int w = 1; w < 1024; w <<= 1) {
        int v = (t >= w) ? part[t - w] : 0;
        __syncthreads();
        part[t] += v;
        __syncthreads();
    }
    int off = (t > 0) ? part[t - 1] : 0;
#pragma unroll
    for (int i = 0; i < 16; ++i) {
        int v = off + loc[i];
        r[t * 16 + i] = v;
        q[t * 16 + i] = v;
    }
    if (t == 1023) r[16384] = part[1023];
}

__global__ __launch_bounds__(256) void k_scatter(const int* __restrict__ sW, const int* __restrict__ dW,
                                                 const int* __restrict__ sC, const int* __restrict__ dC,
                                                 const int* __restrict__ sR, const int* __restrict__ dR,
                                                 int* __restrict__ cur,
                                                 int* __restrict__ eW, int* __restrict__ eC,
                                                 int* __restrict__ eR) {
    int idx = blockIdx.x * 256 + threadIdx.x;   // 3*NE
    int t = idx >> 18, i = idx & (NE - 1);
    const int* sp = t == 0 ? sW : t == 1 ? sC : sR;
    const int* dp = t == 0 ? dW : t == 1 ? dC : dR;
    int* ep = t == 0 ? eW : t == 1 ? eC : eR;
    int pos = atomicAdd(cur + t * 16384 + dp[i], 1);
    ep[pos] = sp[i];
}

// ---------------- batched GEMM (X@W) + el/er head reductions -------
// 4x4 register tile per thread (rows rg*4+i, cols tx*4+q); X staged
// TRANSPOSED (XT[k][row], pad 68 keeps b128 reads aligned+conflict-free);
// W staged in 32-k chunks. Per kk: 2x ds_read_b128 for 16 FMAs.
struct GemmJobs {
    const float* X[5];  const float* W[5];  const float* NT[5];
    float* F[5];        float* EL[5];       float* ER[5];
    const float* AL[5]; const float* AR[5];
};

template <int K, int RELU>
__global__ __launch_bounds__(256) void k_gemm(GemmJobs j) {
    __shared__ float Wc[32 * 64];
    __shared__ float XT[32][68];

    const float* __restrict__ X;  const float* __restrict__ Wp;  const float* __restrict__ NTp;
    float* __restrict__ F;  float* __restrict__ EL;  float* __restrict__ ER;
    const float* __restrict__ AL; const float* __restrict__ AR;
    switch (blockIdx.z) {                         // block-uniform, static indices
      case 0: X=j.X[0]; Wp=j.W[0]; NTp=j.NT[0]; F=j.F[0]; EL=j.EL[0]; ER=j.ER[0]; AL=j.AL[0]; AR=j.AR[0]; break;
      case 1: X=j.X[1]; Wp=j.W[1]; NTp=j.NT[1]; F=j.F[1]; EL=j.EL[1]; ER=j.ER[1]; AL=j.AL[1]; AR=j.AR[1]; break;
      case 2: X=j.X[2]; Wp=j.W[2]; NTp=j.NT[2]; F=j.F[2]; EL=j.EL[2]; ER=j.ER[2]; AL=j.AL[2]; AR=j.AR[2]; break;
      case 3: X=j.X[3]; Wp=j.W[3]; NTp=j.NT[3]; F=j.F[3]; EL=j.EL[3]; ER=j.ER[3]; AL=j.AL[3]; AR=j.AR[3]; break;
      default: X=j.X[4]; Wp=j.W[4]; NTp=j.NT[4]; F=j.F[4]; EL=j.EL[4]; ER=j.ER[4]; AL=j.AL[4]; AR=j.AR[4]; break;
    }

    const int tid = threadIdx.x;
    const int tx  = tid & 15;     // col group: cols tx*4..tx*4+3
    const int rg  = tid >> 4;     // row group: rows rg*4..rg*4+3
    const int r0  = blockIdx.x * 64;

    float acc[4][4] = {};

    for (int kc = 0; kc < K; kc += 32) {
        __syncthreads();
        // stage W chunk (32x64)
#pragma unroll
        for (int it = 0; it < 2; ++it) {
            int idx = tid * 4 + it * 1024;
            int k = idx >> 6, c = idx & 63;
            *(float4*)(Wc + idx) = *(const float4*)(Wp + (size_t)(kc + k) * 64 + c);
        }
        // stage X chunk transposed (XT[k][row])
#pragma unroll
        for (int it = 0; it < 2; ++it) {
            int idx = tid * 4 + it * 1024;
            int row = idx >> 5, col = idx & 31;
            float4 v = *(const float4*)(X + (size_t)(r0 + row) * K + kc + col);
            if (RELU) {
                v.x = fmaxf(v.x, 0.f); v.y = fmaxf(v.y, 0.f);
                v.z = fmaxf(v.z, 0.f); v.w = fmaxf(v.w, 0.f);
            }
            if (NTp) {
                float4 s = *(const float4*)(NTp + kc + col);
                v.x *= s.x; v.y *= s.y; v.z *= s.z; v.w *= s.w;
            }
            XT[col + 0][row] = v.x;
            XT[col + 1][row] = v.y;
            XT[col + 2][row] = v.z;
            XT[col + 3][row] = v.w;
        }
        __syncthreads();
#pragma unroll
        for (int kk = 0; kk < 32; ++kk) {
            float4 a4 = *(const float4*)(&XT[kk][rg * 4]);
            float4 w4 = *(const float4*)(Wc + kk * 64 + tx * 4);
            acc[0][0] = fmaf(a4.x, w4.x, acc[0][0]); acc[0][1] = fmaf(a4.x, w4.y, acc[0][1]);
            acc[0][2] = fmaf(a4.x, w4.z, acc[0][2]); acc[0][3] = fmaf(a4.x, w4.w, acc[0][3]);
            acc[1][0] = fmaf(a4.y, w4.x, acc[1][0]); acc[1][1] = fmaf(a4.y, w4.y, acc[1][1]);
            acc[1][2] = fmaf(a4.y, w4.z, acc[1][2]); acc[1][3] = fmaf(a4.y, w4.w, acc[1][3]);
            acc[2][0] = fmaf(a4.z, w4.x, acc[2][0]); acc[2][1] = fmaf(a4.z, w4.y, acc[2][1]);
            acc[2][2] = fmaf(a4.z, w4.z, acc[2][2]); acc[2][3] = fmaf(a4.z, w4.w, acc[2][3]);
            acc[3][0] = fmaf(a4.w, w4.x, acc[3][0]); acc[3][1] = fmaf(a4.w, w4.y, acc[3][1]);
            acc[3][2] = fmaf(a4.w, w4.z, acc[3][2]); acc[3][3] = fmaf(a4.w, w4.w, acc[3][3]);
        }
    }

    if (F) {
#pragma unroll
        for (int i = 0; i < 4; ++i) {
            size_t n = (size_t)r0 + rg * 4 + i;
            *(float4*)(F + n * 64 + tx * 4) =
                make_float4(acc[i][0], acc[i][1], acc[i][2], acc[i][3]);
        }
    }
    // el/er: thread's 4 cols belong to head tx>>2; reduce over the 4 lanes of
    // the head group (lane bits 0,1) via shfl_xor.
    if (EL) {
        float4 alv = ((const float4*)AL)[tx];
#pragma unroll
        for (int i = 0; i < 4; ++i) {
            float p = acc[i][0] * alv.x + acc[i][1] * alv.y +
                      acc[i][2] * alv.z + acc[i][3] * alv.w;
            p += __shfl_xor(p, 1, 64);
            p += __shfl_xor(p, 2, 64);
            if ((tx & 3) == 0) EL[((size_t)r0 + rg * 4 + i) * 4 + (tx >> 2)] = p;
        }
    }
    if (ER) {
        float4 arv = ((const float4*)AR)[tx];
#pragma unroll
        for (int i = 0; i < 4; ++i) {
            float p = acc[i][0] * arv.x + acc[i][1] * arv.y +
                      acc[i][2] * arv.z + acc[i][3] * arv.w;
            p += __shfl_xor(p, 1, 64);
            p += __shfl_xor(p, 2, 64);
            if ((tx & 3) == 0) ER[((size_t)r0 + rg * 4 + i) * 4 + (tx >> 2)] = p;
        }
    }
}

// ---------------- per-destination gather aggregation (no atomics) ----------
// SINGLE-PASS (softmax shift-invariance; |e| <~ 6 << 88 so exp(e) is safe):
// w=exp(e), den and unnormalized feature sum accumulate together, one
// normalize at the end. Inner 16-edge loop is BRANCH-FREE (padding slots
// carry w=0) — the R7 per-iteration break serialized the loop and cost +15%.
struct AggType { const int* row; const int* es; const float* el; const float* er; const float* fs; };
struct AggArgs { AggType t[3]; const float* b; float* op; float* oa; };

__device__ __forceinline__ float agg16(const int* __restrict__ rowv, const int* __restrict__ es,
                                       const float* __restrict__ el, const float* __restrict__ er,
                                       const float* __restrict__ fs, int d, int lane) {
    int start = rowv[d], end = rowv[d + 1];
    int deg = end - start;
    if (deg <= 0) return 0.f;
    const int g = lane >> 4, j16 = lane & 15;
    const float rh = er[(size_t)d * 4 + g];

    float den = 0.f, acc = 0.f;
    for (int e0 = 0; e0 < deg; e0 += 16) {
        int o = e0 + j16;
        int sn = es[start + (o < deg ? o : 0)];
        float wv = 0.f;
        if (o < deg) wv = __expf(lrelu(el[(size_t)sn * 4 + g] + rh));
        den += wv;
#pragma unroll
        for (int jj = 0; jj < 16; ++jj) {
            int snj = __shfl(sn, jj, 64);                    // edge jj's src (readlane)
            float wj = __shfl(wv, (lane & 48) + jj, 64);     // head-specific weight
            acc = fmaf(wj, fs[(size_t)snj * 64 + lane], acc);
        }
    }
#pragma unroll
    for (int w = 1; w < 16; w <<= 1) den += __shfl_xor(den, w, 64);
    return acc * (1.f / fmaxf(den, 1e-9f));
}

__global__ __launch_bounds__(256) void k_agg(AggArgs A) {
    int wid = (blockIdx.x * 256 + threadIdx.x) >> 6;  // one wave per dst node
    int lane = threadIdx.x & 63;
    if (wid < N_P) {
        // paper node: writes-GAT + cites-GAT (+ both biases)
        float acc = A.b[lane] + A.b[64 + lane];
        acc += agg16(A.t[0].row, A.t[0].es, A.t[0].el, A.t[0].er, A.t[0].fs, wid, lane);
        acc += agg16(A.t[1].row, A.t[1].es, A.t[1].el, A.t[1].er, A.t[1].fs, wid, lane);
        A.op[(size_t)wid * 64 + lane] = acc;
    } else {
        int d = wid - N_P;
        float acc = A.b[128 + lane];
        acc += agg16(A.t[2].row, A.t[2].es, A.t[2].el, A.t[2].er, A.t[2].fs, d, lane);
        A.oa[(size_t)d * 64 + lane] = acc;
    }
}

// ---------------- hf build: h2 = h1 + C, row l2-normalize, concat ------------
__global__ __launch_bounds__(256) void k_hf(const float* __restrict__ h1, float* __restrict__ hf,
                                            const float* __restrict__ ln1gb,
                                            const float* __restrict__ aw, const float* __restrict__ ab,
                                            const float* __restrict__ ln2gb,
                                            const float* __restrict__ fw1, const float* __restrict__ fb1,
                                            const float* __restrict__ fw2, const float* __restrict__ fb2) {
    __shared__ float Cs;
    if (threadIdx.x == 0) {
        // LN over size-1 axis -> exactly its bias term
        float y1 = ln1gb[1];
        float v  = y1 * aw[2] + ab[2];          // v constant; softmax uniform -> o = v
        float o  = v * aw[3] + ab[3];
        float y2 = ln2gb[1];
        float f  = fb2[0];
#pragma unroll
        for (int q = 0; q < 16; ++q) {
            float zz = y2 * fw1[q] + fb1[q];
            f += 0.5f * zz * (1.f + erff(zz * 0.70710678118654752f)) * fw2[q];
        }
        Cs = o + f;
    }
    __syncthreads();
    float C = Cs;
    int lane = threadIdx.x & 63;
    int row  = blockIdx.x * 4 + (threadIdx.x >> 6);
    float v1 = h1[(size_t)row * 64 + lane];
    float s1 = v1 * v1;
#pragma unroll
    for (int w = 1; w < 64; w <<= 1) s1 += __shfl_xor(s1, w, 64);
    float o1 = v1 / fmaxf(sqrtf(s1), 1e-12f);
    float v2 = v1 + C;
    float s2 = v2 * v2;
#pragma unroll
    for (int w = 1; w < 64; w <<= 1) s2 += __shfl_xor(s2, w, 64);
    float o2 = v2 / fmaxf(sqrtf(s2), 1e-12f);
    hf[(size_t)row * 128 + lane]      = o1;
    hf[(size_t)row * 128 + 64 + lane] = o2;
}

// ---------------- final GEMM: out = hf(16384x128) @ linW(128x349) + linb -----
// Same 4x4 register-tile structure as k_gemm (W chunked, XT transposed).
__global__ __launch_bounds__(256) void k_gemm_out(const float* __restrict__ X,
                                                  const float* __restrict__ W,
                                                  const float* __restrict__ bias,
                                                  float* __restrict__ out) {
    __shared__ float Wc[32 * 64];
    __shared__ float XT[32][68];
    const int tid = threadIdx.x;
    const int tx  = tid & 15;
    const int rg  = tid >> 4;
    const int r0  = blockIdx.x * 64;
    const int c0  = blockIdx.y * 64;

    float acc[4][4] = {};

    for (int kc = 0; kc < 128; kc += 32) {
        __syncthreads();
#pragma unroll
        for (int it = 0; it < 2; ++it) {
            int idx = tid * 4 + it * 1024;
            int k = idx >> 6, c = idx & 63;
            int gk = kc + k;
            float4 v;
            int gc = c0 + c;
            v.x = (gc + 0 < OUTD) ? W[(size_t)gk * OUTD + gc + 0] : 0.f;
            v.y = (gc + 1 < OUTD) ? W[(size_t)gk * OUTD + gc + 1] : 0.f;
            v.z = (gc + 2 < OUTD) ? W[(size_t)gk * OUTD + gc + 2] : 0.f;
            v.w = (gc + 3 < OUTD) ? W[(size_t)gk * OUTD + gc + 3] : 0.f;
            *(float4*)(Wc + idx) = v;
        }
#pragma unroll
        for (int it = 0; it < 2; ++it) {
            int idx = tid * 4 + it * 1024;
            int row = idx >> 5, col = idx & 31;
            float4 v = *(const float4*)(X + (size_t)(r0 + row) * 128 + kc + col);
            XT[col + 0][row] = v.x;
            XT[col + 1][row] = v.y;
            XT[col + 2][row] = v.z;
            XT[col + 3][row] = v.w;
        }
        __syncthreads();
#pragma unroll
        for (int kk = 0; kk < 32; ++kk) {
            float4 a4 = *(const float4*)(&XT[kk][rg * 4]);
            float4 w4 = *(const float4*)(Wc + kk * 64 + tx * 4);
            acc[0][0] = fmaf(a4.x, w4.x, acc[0][0]); acc[0][1] = fmaf(a4.x, w4.y, acc[0][1]);
            acc[0][2] = fmaf(a4.x, w4.z, acc[0][2]); acc[0][3] = fmaf(a4.x, w4.w, acc[0][3]);
            acc[1][0] = fmaf(a4.y, w4.x, acc[1][0]); acc[1][1] = fmaf(a4.y, w4.y, acc[1][1]);
            acc[1][2] = fmaf(a4.y, w4.z, acc[1][2]); acc[1][3] = fmaf(a4.y, w4.w, acc[1][3]);
            acc[2][0] = fmaf(a4.z, w4.x, acc[2][0]); acc[2][1] = fmaf(a4.z, w4.y, acc[2][1]);
            acc[2][2] = fmaf(a4.z, w4.z, acc[2][2]); acc[2][3] = fmaf(a4.z, w4.w, acc[2][3]);
            acc[3][0] = fmaf(a4.w, w4.x, acc[3][0]); acc[3][1] = fmaf(a4.w, w4.y, acc[3][1]);
            acc[3][2] = fmaf(a4.w, w4.z, acc[3][2]); acc[3][3] = fmaf(a4.w, w4.w, acc[3][3]);
        }
    }

    float b4[4];
#pragma unroll
    for (int q = 0; q < 4; ++q) {
        int c = c0 + tx * 4 + q;
        b4[q] = (c < OUTD) ? bias[c] : 0.f;
    }
#pragma unroll
    for (int i = 0; i < 4; ++i) {
        size_t n = (size_t)r0 + rg * 4 + i;
#pragma unroll
        for (int q = 0; q < 4; ++q) {
            int c = c0 + tx * 4 + q;
            if (c < OUTD) out[n * OUTD + c] = acc[i][q] + b4[q];
        }
    }
}

// ---------------- host ----------------
extern "C" void kernel_launch(void* const* d_in, const int* in_sizes, int n_in,
                              void* d_out, int out_size, void* d_ws, size_t ws_size,
                              hipStream_t stream) {
    const float* x_author = (const float*)d_in[0];
    const float* x_paper  = (const float*)d_in[1];
    const float* ntype    = (const float*)d_in[2];
    const float* W0  = (const float*)d_in[3];
    const float* al0 = (const float*)d_in[4];
    const float* ar0 = (const float*)d_in[5];
    const float* b0  = (const float*)d_in[6];
    const float* W1  = (const float*)d_in[7];
    const float* al1 = (const float*)d_in[8];
    const float* ar1 = (const float*)d_in[9];
    const float* b1  = (const float*)d_in[10];
    const float* ln1gb = (const float*)d_in[11];
    const float* attw  = (const float*)d_in[12];
    const float* attb  = (const float*)d_in[13];
    const float* ln2gb = (const float*)d_in[14];
    const float* fw1 = (const float*)d_in[15];
    const float* fb1 = (const float*)d_in[16];
    const float* fw2 = (const float*)d_in[17];
    const float* fb2 = (const float*)d_in[18];
    const float* linW = (const float*)d_in[19];
    const float* linb = (const float*)d_in[20];
    const int* srcW = (const int*)d_in[21];
    const int* dstW = (const int*)d_in[22];
    const int* srcC = (const int*)d_in[23];
    const int* dstC = (const int*)d_in[24];
    const int* srcR = (const int*)d_in[25];
    const int* dstR = (const int*)d_in[26];
    float* out = (float*)d_out;

    // ---- workspace carve-up ----
    float* ws = (float*)d_ws;
    size_t off = 0;
    float* fsW = ws + off; off += (size_t)N_A * HID;
    float* fsC = ws + off; off += (size_t)N_P * HID;
    float* fsR = ws + off; off += (size_t)N_P * HID;
    float* elw = ws + off; off += (size_t)N_A * NH;
    float* erw = ws + off; off += (size_t)N_P * NH;
    float* elc = ws + off; off += (size_t)N_P * NH;
    float* erc = ws + off; off += (size_t)N_P * NH;
    float* elr = ws + off; off += (size_t)N_P * NH;
    float* err = ws + off; off += (size_t)N_A * NH;
    float* oa0 = ws + off; off += (size_t)N_A * HID;
    float* op0 = ws + off; off += (size_t)N_P * HID;
    float* oa1 = ws + off; off += (size_t)N_A * HID;
    float* op1 = ws + off; off += (size_t)N_P * HID;
    float* hf  = ws + off; off += (size_t)N_P * 2 * HID;
    int* cnt  = (int*)(ws + off); off += 3 * 16384;
    int* row  = (int*)(ws + off); off += 3 * 16385 + 1;   // +1 keeps alignment slack
    int* cur  = (int*)(ws + off); off += 3 * 16384;
    int* esW  = (int*)(ws + off); off += NE;
    int* esC  = (int*)(ws + off); off += NE;
    int* esR  = (int*)(ws + off); off += NE;

    const int* rowW = row;
    const int* rowC = row + 16385;
    const int* rowR = row + 2 * 16385;

    const float* ntA = ntype;            // author scale row (128)
    const float* ntP = ntype + IN_D;     // paper scale row

    // ---- layer job tables (layer 0 reads raw x, scaled by NT on load) ----
    GemmJobs j0{};
    j0.X[0] = x_author; j0.W[0] = W0;                  j0.NT[0] = ntA;
    j0.F[0] = fsW; j0.EL[0] = elw; j0.ER[0] = nullptr; j0.AL[0] = al0;       j0.AR[0] = nullptr;
    j0.X[1] = x_paper;  j0.W[1] = W0;                  j0.NT[1] = ntP;
    j0.F[1] = nullptr; j0.EL[1] = nullptr; j0.ER[1] = erw; j0.AL[1] = nullptr; j0.AR[1] = ar0;
    j0.X[2] = x_paper;  j0.W[2] = W0 + IN_D * HID;     j0.NT[2] = ntP;
    j0.F[2] = fsC; j0.EL[2] = elc; j0.ER[2] = erc;     j0.AL[2] = al0 + 64;  j0.AR[2] = ar0 + 64;
    j0.X[3] = x_paper;  j0.W[3] = W0 + 2 * IN_D * HID; j0.NT[3] = ntP;
    j0.F[3] = fsR; j0.EL[3] = elr; j0.ER[3] = nullptr; j0.AL[3] = al0 + 128; j0.AR[3] = nullptr;
    j0.X[4] = x_author; j0.W[4] = W0 + 2 * IN_D * HID; j0.NT[4] = ntA;
    j0.F[4] = nullptr; j0.EL[4] = nullptr; j0.ER[4] = err; j0.AL[4] = nullptr; j0.AR[4] = ar0 + 128;

    GemmJobs j1{};
    j1.X[0] = oa0; j1.W[0] = W1;                   j1.NT[0] = nullptr;
    j1.F[0] = fsW; j1.EL[0] = elw; j1.ER[0] = nullptr; j1.AL[0] = al1;       j1.AR[0] = nullptr;
    j1.X[1] = op0; j1.W[1] = W1;                   j1.NT[1] = nullptr;
    j1.F[1] = nullptr; j1.EL[1] = nullptr; j1.ER[1] = erw; j1.AL[1] = nullptr; j1.AR[1] = ar1;
    j1.X[2] = op0; j1.W[2] = W1 + HID * HID;       j1.NT[2] = nullptr;
    j1.F[2] = fsC; j1.EL[2] = elc; j1.ER[2] = erc;     j1.AL[2] = al1 + 64;  j1.AR[2] = ar1 + 64;
    j1.X[3] = op0; j1.W[3] = W1 + 2 * HID * HID;   j1.NT[3] = nullptr;
    j1.F[3] = fsR; j1.EL[3] = elr; j1.ER[3] = nullptr; j1.AL[3] = al1 + 128; j1.AR[3] = nullptr;
    j1.X[4] = oa0; j1.W[4] = W1 + 2 * HID * HID;   j1.NT[4] = nullptr;
    j1.F[4] = nullptr; j1.EL[4] = nullptr; j1.ER[4] = err; j1.AL[4] = nullptr; j1.AR[4] = ar1 + 128;

    AggArgs a0{};
    a0.t[0] = {rowW, esW, elw, erw, fsW};
    a0.t[1] = {rowC, esC, elc, erc, fsC};
    a0.t[2] = {rowR, esR, elr, err, fsR};
    a0.b = b0; a0.op = op0; a0.oa = oa0;
    AggArgs a1 = a0;
    a1.b = b1; a1.op = op1; a1.oa = oa1;

    // ---- launches ----
    // CSR build (edge lists constant across layers)
    k_zero<<<(3 * 16384 + 255) / 256, 256, 0, stream>>>(cnt);
    k_hist<<<3 * NE / 256, 256, 0, stream>>>(dstW, dstC, dstR, cnt);
    k_scan<<<3, 1024, 0, stream>>>(cnt, row, cur);
    k_scatter<<<3 * NE / 256, 256, 0, stream>>>(srcW, dstW, srcC, dstC, srcR, dstR, cur, esW, esC, esR);

    // layer 0 (ntype scale folded into X load)
    k_gemm<IN_D, 0><<<dim3(N_A / 64, 1, 5), 256, 0, stream>>>(j0);
    k_agg<<<(N_P + N_A) / 4, 256, 0, stream>>>(a0);

    // layer 1 (relu folded into GEMM X loads)
    k_gemm<HID, 1><<<dim3(N_A / 64, 1, 5), 256, 0, stream>>>(j1);
    k_agg<<<(N_P + N_A) / 4, 256, 0, stream>>>(a1);

    // epilogue
    k_hf<<<N_P / 4, 256, 0, stream>>>(op1, hf, ln1gb, attw, attb, ln2gb, fw1, fb1, fw2, fb2);
    k_gemm_out<<<dim3(N_P / 64, (OUTD + 63) / 64), 256, 0, stream>>>(hf, linW, linb, out);
}

// Round 9
// 171.099 us; speedup vs baseline: 1.5480x; 1.3180x over previous
//
#include <hip/hip_runtime.h>
#include <math.h>

// ---------------- problem constants ----------------
constexpr int N_A   = 16384;
constexpr int N_P   = 16384;
constexpr int IN_D  = 128;
constexpr int HID   = 64;
constexpr int NH    = 4;    // heads
constexpr int OUTD  = 349;
constexpr int NE    = 262144; // edges per type (2^18)
constexpr int NB    = 64;     // coarse-partition blocks per type (4096 edges each)
constexpr float NEG = 0.2f;

__device__ __forceinline__ float lrelu(float x) { return x > 0.f ? x : NEG * x; }

// ---------------- CSR build: two-level coherent partition ----------------
// Old single-level atomic scatter wrote 41 MB HBM for a 3 MB payload (each
// bucket's slots written from ~16 different blocks/XCDs -> 64B-line ping-pong;
// measured R8: 42.6us, VALU 1.2%). New scheme: coarse 256-bucket partition with
// block-private contiguous runs (full-line writes), then per-coarse-bucket
// LDS counting sort producing final es + row.

// coarse histogram: ccnt[(t*NB+blk)*256 + bin]
__global__ __launch_bounds__(256) void k_chist(const int* __restrict__ dW, const int* __restrict__ dC,
                                               const int* __restrict__ dR, int* __restrict__ ccnt) {
    __shared__ int h[256];
    const int t = blockIdx.y;
    const int* __restrict__ d = t == 0 ? dW : t == 1 ? dC : dR;
    const int tid = threadIdx.x;
    h[tid] = 0;
    __syncthreads();
    const int base = blockIdx.x * 4096;
#pragma unroll
    for (int i = 0; i < 16; ++i) {
        int dst = d[base + i * 256 + tid];
        atomicAdd(&h[dst >> 6], 1);
    }
    __syncthreads();
    ccnt[(t * NB + blockIdx.x) * 256 + tid] = h[tid];
}

// single block, 768 threads = (type, bin). totals -> segmented exclusive scan
// -> crow (coarse row) and per-block run offsets coffs.
__global__ __launch_bounds__(768) void k_coffs(const int* __restrict__ ccnt, int* __restrict__ coffs,
                                               int* __restrict__ crow) {
    const int tid = threadIdx.x;
    const int t = tid >> 8, bin = tid & 255;
    int total = 0;
    for (int b = 0; b < NB; ++b) total += ccnt[(t * NB + b) * 256 + bin];
    __shared__ int sc[768];
    sc[tid] = total;
    __syncthreads();
    for (int w = 1; w < 256; w <<= 1) {
        int v = (bin >= w) ? sc[tid - w] : 0;
        __syncthreads();
        sc[tid] += v;
        __syncthreads();
    }
    const int incl = sc[tid];
    const int base = incl - total;       // exclusive prefix within type
    crow[t * 257 + bin] = base;
    if (bin == 255) crow[t * 257 + 256] = incl;   // == NE
    int run = base;
    for (int b = 0; b < NB; ++b) {
        int c = ccnt[(t * NB + b) * 256 + bin];
        coffs[(t * NB + b) * 256 + bin] = run;
        run += c;
    }
}

// coarse scatter into block-private contiguous runs; payload packs
// src (14b) | (dst&63)<<14 into one int.
__global__ __launch_bounds__(256) void k_cscatter(const int* __restrict__ sW, const int* __restrict__ dW,
                                                  const int* __restrict__ sC, const int* __restrict__ dC,
                                                  const int* __restrict__ sR, const int* __restrict__ dR,
                                                  const int* __restrict__ coffs,
                                                  int* __restrict__ ebW, int* __restrict__ ebC,
                                                  int* __restrict__ ebR) {
    __shared__ int cur[256];
    const int t = blockIdx.y;
    const int* __restrict__ sp = t == 0 ? sW : t == 1 ? sC : sR;
    const int* __restrict__ dp = t == 0 ? dW : t == 1 ? dC : dR;
    int* __restrict__ eb = t == 0 ? ebW : t == 1 ? ebC : ebR;
    const int tid = threadIdx.x;
    cur[tid] = coffs[(t * NB + blockIdx.x) * 256 + tid];
    __syncthreads();
    const int base = blockIdx.x * 4096;
#pragma unroll
    for (int i = 0; i < 16; ++i) {
        int e = base + i * 256 + tid;
        int dst = dp[e], src = sp[e];
        int pos = atomicAdd(&cur[dst >> 6], 1);
        eb[pos] = src | ((dst & 63) << 14);
    }
}

// fine pass: one block per (type, coarse bucket). 64-bin counting sort of the
// self-contained region -> final es (contiguous writes) + exact row[].
__global__ __launch_bounds__(256) void k_fine(const int* __restrict__ crow,
                                              const int* __restrict__ ebW, const int* __restrict__ ebC,
                                              const int* __restrict__ ebR,
                                              int* __restrict__ row,
                                              int* __restrict__ esW, int* __restrict__ esC,
                                              int* __restrict__ esR) {
    __shared__ int bins[64], exc[64], cur[64];
    const int t = blockIdx.y, cb = blockIdx.x, tid = threadIdx.x;
    const int* __restrict__ eb = t == 0 ? ebW : t == 1 ? ebC : ebR;
    int* __restrict__ es = t == 0 ? esW : t == 1 ? esC : esR;
    const int lo = crow[t * 257 + cb], hi = crow[t * 257 + cb + 1];
    if (tid < 64) bins[tid] = 0;
    __syncthreads();
    for (int e = lo + tid; e < hi; e += 256) atomicAdd(&bins[eb[e] >> 14], 1);
    __syncthreads();
    if (tid == 0) {
        int r = 0;
#pragma unroll
        for (int j = 0; j < 64; ++j) { exc[j] = r; cur[j] = r; r += bins[j]; }
    }
    __syncthreads();
    if (tid < 64) row[t * 16385 + cb * 64 + tid] = lo + exc[tid];
    if (tid == 0 && cb == 255) row[t * 16385 + 16384] = crow[t * 257 + 256];
    for (int e = lo + tid; e < hi; e += 256) {
        int v = eb[e];
        int pos = atomicAdd(&cur[v >> 14], 1);
        es[lo + pos] = v & 16383;
    }
}

// ---------------- batched GEMM (X@W) + el/er head reductions -------
// 4x4 register tile per thread (rows rg*4+i, cols tx*4+q); X staged
// TRANSPOSED (XT[k][row], pad 68 keeps b128 reads aligned+conflict-free);
// W staged in 32-k chunks. Per kk: 2x ds_read_b128 for 16 FMAs.
struct GemmJobs {
    const float* X[5];  const float* W[5];  const float* NT[5];
    float* F[5];        float* EL[5];       float* ER[5];
    const float* AL[5]; const float* AR[5];
};

template <int K, int RELU>
__global__ __launch_bounds__(256) void k_gemm(GemmJobs j) {
    __shared__ float Wc[32 * 64];
    __shared__ float XT[32][68];

    const float* __restrict__ X;  const float* __restrict__ Wp;  const float* __restrict__ NTp;
    float* __restrict__ F;  float* __restrict__ EL;  float* __restrict__ ER;
    const float* __restrict__ AL; const float* __restrict__ AR;
    switch (blockIdx.z) {                         // block-uniform, static indices
      case 0: X=j.X[0]; Wp=j.W[0]; NTp=j.NT[0]; F=j.F[0]; EL=j.EL[0]; ER=j.ER[0]; AL=j.AL[0]; AR=j.AR[0]; break;
      case 1: X=j.X[1]; Wp=j.W[1]; NTp=j.NT[1]; F=j.F[1]; EL=j.EL[1]; ER=j.ER[1]; AL=j.AL[1]; AR=j.AR[1]; break;
      case 2: X=j.X[2]; Wp=j.W[2]; NTp=j.NT[2]; F=j.F[2]; EL=j.EL[2]; ER=j.ER[2]; AL=j.AL[2]; AR=j.AR[2]; break;
      case 3: X=j.X[3]; Wp=j.W[3]; NTp=j.NT[3]; F=j.F[3]; EL=j.EL[3]; ER=j.ER[3]; AL=j.AL[3]; AR=j.AR[3]; break;
      default: X=j.X[4]; Wp=j.W[4]; NTp=j.NT[4]; F=j.F[4]; EL=j.EL[4]; ER=j.ER[4]; AL=j.AL[4]; AR=j.AR[4]; break;
    }

    const int tid = threadIdx.x;
    const int tx  = tid & 15;     // col group: cols tx*4..tx*4+3
    const int rg  = tid >> 4;     // row group: rows rg*4..rg*4+3
    const int r0  = blockIdx.x * 64;

    float acc[4][4] = {};

    for (int kc = 0; kc < K; kc += 32) {
        __syncthreads();
        // stage W chunk (32x64)
#pragma unroll
        for (int it = 0; it < 2; ++it) {
            int idx = tid * 4 + it * 1024;
            int k = idx >> 6, c = idx & 63;
            *(float4*)(Wc + idx) = *(const float4*)(Wp + (size_t)(kc + k) * 64 + c);
        }
        // stage X chunk transposed (XT[k][row])
#pragma unroll
        for (int it = 0; it < 2; ++it) {
            int idx = tid * 4 + it * 1024;
            int row = idx >> 5, col = idx & 31;
            float4 v = *(const float4*)(X + (size_t)(r0 + row) * K + kc + col);
            if (RELU) {
                v.x = fmaxf(v.x, 0.f); v.y = fmaxf(v.y, 0.f);
                v.z = fmaxf(v.z, 0.f); v.w = fmaxf(v.w, 0.f);
            }
            if (NTp) {
                float4 s = *(const float4*)(NTp + kc + col);
                v.x *= s.x; v.y *= s.y; v.z *= s.z; v.w *= s.w;
            }
            XT[col + 0][row] = v.x;
            XT[col + 1][row] = v.y;
            XT[col + 2][row] = v.z;
            XT[col + 3][row] = v.w;
        }
        __syncthreads();
#pragma unroll
        for (int kk = 0; kk < 32; ++kk) {
            float4 a4 = *(const float4*)(&XT[kk][rg * 4]);
            float4 w4 = *(const float4*)(Wc + kk * 64 + tx * 4);
            acc[0][0] = fmaf(a4.x, w4.x, acc[0][0]); acc[0][1] = fmaf(a4.x, w4.y, acc[0][1]);
            acc[0][2] = fmaf(a4.x, w4.z, acc[0][2]); acc[0][3] = fmaf(a4.x, w4.w, acc[0][3]);
            acc[1][0] = fmaf(a4.y, w4.x, acc[1][0]); acc[1][1] = fmaf(a4.y, w4.y, acc[1][1]);
            acc[1][2] = fmaf(a4.y, w4.z, acc[1][2]); acc[1][3] = fmaf(a4.y, w4.w, acc[1][3]);
            acc[2][0] = fmaf(a4.z, w4.x, acc[2][0]); acc[2][1] = fmaf(a4.z, w4.y, acc[2][1]);
            acc[2][2] = fmaf(a4.z, w4.z, acc[2][2]); acc[2][3] = fmaf(a4.z, w4.w, acc[2][3]);
            acc[3][0] = fmaf(a4.w, w4.x, acc[3][0]); acc[3][1] = fmaf(a4.w, w4.y, acc[3][1]);
            acc[3][2] = fmaf(a4.w, w4.z, acc[3][2]); acc[3][3] = fmaf(a4.w, w4.w, acc[3][3]);
        }
    }

    if (F) {
#pragma unroll
        for (int i = 0; i < 4; ++i) {
            size_t n = (size_t)r0 + rg * 4 + i;
            *(float4*)(F + n * 64 + tx * 4) =
                make_float4(acc[i][0], acc[i][1], acc[i][2], acc[i][3]);
        }
    }
    // el/er: thread's 4 cols belong to head tx>>2; reduce over the 4 lanes of
    // the head group (lane bits 0,1) via shfl_xor.
    if (EL) {
        float4 alv = ((const float4*)AL)[tx];
#pragma unroll
        for (int i = 0; i < 4; ++i) {
            float p = acc[i][0] * alv.x + acc[i][1] * alv.y +
                      acc[i][2] * alv.z + acc[i][3] * alv.w;
            p += __shfl_xor(p, 1, 64);
            p += __shfl_xor(p, 2, 64);
            if ((tx & 3) == 0) EL[((size_t)r0 + rg * 4 + i) * 4 + (tx >> 2)] = p;
        }
    }
    if (ER) {
        float4 arv = ((const float4*)AR)[tx];
#pragma unroll
        for (int i = 0; i < 4; ++i) {
            float p = acc[i][0] * arv.x + acc[i][1] * arv.y +
                      acc[i][2] * arv.z + acc[i][3] * arv.w;
            p += __shfl_xor(p, 1, 64);
            p += __shfl_xor(p, 2, 64);
            if ((tx & 3) == 0) ER[((size_t)r0 + rg * 4 + i) * 4 + (tx >> 2)] = p;
        }
    }
}

// ---------------- per-destination gather aggregation (no atomics) ----------
// SINGLE-PASS (softmax shift-invariance; |e| <~ 6 << 88 so exp(e) is safe):
// w=exp(e), den and unnormalized feature sum accumulate together, one
// normalize at the end. Inner 16-edge loop is BRANCH-FREE (padding slots
// carry w=0) — a per-iteration break serialized the loop and cost +15% (R7).
struct AggType { const int* row; const int* es; const float* el; const float* er; const float* fs; };
struct AggArgs { AggType t[3]; const float* b; float* op; float* oa; };

__device__ __forceinline__ float agg16(const int* __restrict__ rowv, const int* __restrict__ es,
                                       const float* __restrict__ el, const float* __restrict__ er,
                                       const float* __restrict__ fs, int d, int lane) {
    int start = rowv[d], end = rowv[d + 1];
    int deg = end - start;
    if (deg <= 0) return 0.f;
    const int g = lane >> 4, j16 = lane & 15;
    const float rh = er[(size_t)d * 4 + g];

    float den = 0.f, acc = 0.f;
    for (int e0 = 0; e0 < deg; e0 += 16) {
        int o = e0 + j16;
        int sn = es[start + (o < deg ? o : 0)];
        float wv = 0.f;
        if (o < deg) wv = __expf(lrelu(el[(size_t)sn * 4 + g] + rh));
        den += wv;
#pragma unroll
        for (int jj = 0; jj < 16; ++jj) {
            int snj = __shfl(sn, jj, 64);                    // edge jj's src (readlane)
            float wj = __shfl(wv, (lane & 48) + jj, 64);     // head-specific weight
            acc = fmaf(wj, fs[(size_t)snj * 64 + lane], acc);
        }
    }
#pragma unroll
    for (int w = 1; w < 16; w <<= 1) den += __shfl_xor(den, w, 64);
    return acc * (1.f / fmaxf(den, 1e-9f));
}

__global__ __launch_bounds__(256) void k_agg(AggArgs A) {
    int wid = (blockIdx.x * 256 + threadIdx.x) >> 6;  // one wave per dst node
    int lane = threadIdx.x & 63;
    if (wid < N_P) {
        // paper node: writes-GAT + cites-GAT (+ both biases)
        float acc = A.b[lane] + A.b[64 + lane];
        acc += agg16(A.t[0].row, A.t[0].es, A.t[0].el, A.t[0].er, A.t[0].fs, wid, lane);
        acc += agg16(A.t[1].row, A.t[1].es, A.t[1].el, A.t[1].er, A.t[1].fs, wid, lane);
        A.op[(size_t)wid * 64 + lane] = acc;
    } else {
        int d = wid - N_P;
        float acc = A.b[128 + lane];
        acc += agg16(A.t[2].row, A.t[2].es, A.t[2].el, A.t[2].er, A.t[2].fs, d, lane);
        A.oa[(size_t)d * 64 + lane] = acc;
    }
}

// ---------------- hf build: h2 = h1 + C, row l2-normalize, concat ------------
__global__ __launch_bounds__(256) void k_hf(const float* __restrict__ h1, float* __restrict__ hf,
                                            const float* __restrict__ ln1gb,
                                            const float* __restrict__ aw, const float* __restrict__ ab,
                                            const float* __restrict__ ln2gb,
                                            const float* __restrict__ fw1, const float* __restrict__ fb1,
                                            const float* __restrict__ fw2, const float* __restrict__ fb2) {
    __shared__ float Cs;
    if (threadIdx.x == 0) {
        // LN over size-1 axis -> exactly its bias term
        float y1 = ln1gb[1];
        float v  = y1 * aw[2] + ab[2];          // v constant; softmax uniform -> o = v
        float o  = v * aw[3] + ab[3];
        float y2 = ln2gb[1];
        float f  = fb2[0];
#pragma unroll
        for (int q = 0; q < 16; ++q) {
            float zz = y2 * fw1[q] + fb1[q];
            f += 0.5f * zz * (1.f + erff(zz * 0.70710678118654752f)) * fw2[q];
        }
        Cs = o + f;
    }
    __syncthreads();
    float C = Cs;
    int lane = threadIdx.x & 63;
    int row  = blockIdx.x * 4 + (threadIdx.x >> 6);
    float v1 = h1[(size_t)row * 64 + lane];
    float s1 = v1 * v1;
#pragma unroll
    for (int w = 1; w < 64; w <<= 1) s1 += __shfl_xor(s1, w, 64);
    float o1 = v1 / fmaxf(sqrtf(s1), 1e-12f);
    float v2 = v1 + C;
    float s2 = v2 * v2;
#pragma unroll
    for (int w = 1; w < 64; w <<= 1) s2 += __shfl_xor(s2, w, 64);
    float o2 = v2 / fmaxf(sqrtf(s2), 1e-12f);
    hf[(size_t)row * 128 + lane]      = o1;
    hf[(size_t)row * 128 + 64 + lane] = o2;
}

// ---------------- final GEMM: out = hf(16384x128) @ linW(128x349) + linb -----
// Same 4x4 register-tile structure as k_gemm (W chunked, XT transposed).
__global__ __launch_bounds__(256) void k_gemm_out(const float* __restrict__ X,
                                                  const float* __restrict__ W,
                                                  const float* __restrict__ bias,
                                                  float* __restrict__ out) {
    __shared__ float Wc[32 * 64];
    __shared__ float XT[32][68];
    const int tid = threadIdx.x;
    const int tx  = tid & 15;
    const int rg  = tid >> 4;
    const int r0  = blockIdx.x * 64;
    const int c0  = blockIdx.y * 64;

    float acc[4][4] = {};

    for (int kc = 0; kc < 128; kc += 32) {
        __syncthreads();
#pragma unroll
        for (int it = 0; it < 2; ++it) {
            int idx = tid * 4 + it * 1024;
            int k = idx >> 6, c = idx & 63;
            int gk = kc + k;
            float4 v;
            int gc = c0 + c;
            v.x = (gc + 0 < OUTD) ? W[(size_t)gk * OUTD + gc + 0] : 0.f;
            v.y = (gc + 1 < OUTD) ? W[(size_t)gk * OUTD + gc + 1] : 0.f;
            v.z = (gc + 2 < OUTD) ? W[(size_t)gk * OUTD + gc + 2] : 0.f;
            v.w = (gc + 3 < OUTD) ? W[(size_t)gk * OUTD + gc + 3] : 0.f;
            *(float4*)(Wc + idx) = v;
        }
#pragma unroll
        for (int it = 0; it < 2; ++it) {
            int idx = tid * 4 + it * 1024;
            int row = idx >> 5, col = idx & 31;
            float4 v = *(const float4*)(X + (size_t)(r0 + row) * 128 + kc + col);
            XT[col + 0][row] = v.x;
            XT[col + 1][row] = v.y;
            XT[col + 2][row] = v.z;
            XT[col + 3][row] = v.w;
        }
        __syncthreads();
#pragma unroll
        for (int kk = 0; kk < 32; ++kk) {
            float4 a4 = *(const float4*)(&XT[kk][rg * 4]);
            float4 w4 = *(const float4*)(Wc + kk * 64 + tx * 4);
            acc[0][0] = fmaf(a4.x, w4.x, acc[0][0]); acc[0][1] = fmaf(a4.x, w4.y, acc[0][1]);
            acc[0][2] = fmaf(a4.x, w4.z, acc[0][2]); acc[0][3] = fmaf(a4.x, w4.w, acc[0][3]);
            acc[1][0] = fmaf(a4.y, w4.x, acc[1][0]); acc[1][1] = fmaf(a4.y, w4.y, acc[1][1]);
            acc[1][2] = fmaf(a4.y, w4.z, acc[1][2]); acc[1][3] = fmaf(a4.y, w4.w, acc[1][3]);
            acc[2][0] = fmaf(a4.z, w4.x, acc[2][0]); acc[2][1] = fmaf(a4.z, w4.y, acc[2][1]);
            acc[2][2] = fmaf(a4.z, w4.z, acc[2][2]); acc[2][3] = fmaf(a4.z, w4.w, acc[2][3]);
            acc[3][0] = fmaf(a4.w, w4.x, acc[3][0]); acc[3][1] = fmaf(a4.w, w4.y, acc[3][1]);
            acc[3][2] = fmaf(a4.w, w4.z, acc[3][2]); acc[3][3] = fmaf(a4.w, w4.w, acc[3][3]);
        }
    }

    float b4[4];
#pragma unroll
    for (int q = 0; q < 4; ++q) {
        int c = c0 + tx * 4 + q;
        b4[q] = (c < OUTD) ? bias[c] : 0.f;
    }
#pragma unroll
    for (int i = 0; i < 4; ++i) {
        size_t n = (size_t)r0 + rg * 4 + i;
#pragma unroll
        for (int q = 0; q < 4; ++q) {
            int c = c0 + tx * 4 + q;
            if (c < OUTD) out[n * OUTD + c] = acc[i][q] + b4[q];
        }
    }
}

// ---------------- host ----------------
extern "C" void kernel_launch(void* const* d_in, const int* in_sizes, int n_in,
                              void* d_out, int out_size, void* d_ws, size_t ws_size,
                              hipStream_t stream) {
    const float* x_author = (const float*)d_in[0];
    const float* x_paper  = (const float*)d_in[1];
    const float* ntype    = (const float*)d_in[2];
    const float* W0  = (const float*)d_in[3];
    const float* al0 = (const float*)d_in[4];
    const float* ar0 = (const float*)d_in[5];
    const float* b0  = (const float*)d_in[6];
    const float* W1  = (const float*)d_in[7];
    const float* al1 = (const float*)d_in[8];
    const float* ar1 = (const float*)d_in[9];
    const float* b1  = (const float*)d_in[10];
    const float* ln1gb = (const float*)d_in[11];
    const float* attw  = (const float*)d_in[12];
    const float* attb  = (const float*)d_in[13];
    const float* ln2gb = (const float*)d_in[14];
    const float* fw1 = (const float*)d_in[15];
    const float* fb1 = (const float*)d_in[16];
    const float* fw2 = (const float*)d_in[17];
    const float* fb2 = (const float*)d_in[18];
    const float* linW = (const float*)d_in[19];
    const float* linb = (const float*)d_in[20];
    const int* srcW = (const int*)d_in[21];
    const int* dstW = (const int*)d_in[22];
    const int* srcC = (const int*)d_in[23];
    const int* dstC = (const int*)d_in[24];
    const int* srcR = (const int*)d_in[25];
    const int* dstR = (const int*)d_in[26];
    float* out = (float*)d_out;

    // ---- workspace carve-up ----
    float* ws = (float*)d_ws;
    size_t off = 0;
    float* fsW = ws + off; off += (size_t)N_A * HID;
    float* fsC = ws + off; off += (size_t)N_P * HID;
    float* fsR = ws + off; off += (size_t)N_P * HID;
    float* elw = ws + off; off += (size_t)N_A * NH;
    float* erw = ws + off; off += (size_t)N_P * NH;
    float* elc = ws + off; off += (size_t)N_P * NH;
    float* erc = ws + off; off += (size_t)N_P * NH;
    float* elr = ws + off; off += (size_t)N_P * NH;
    float* err = ws + off; off += (size_t)N_A * NH;
    float* oa0 = ws + off; off += (size_t)N_A * HID;
    float* op0 = ws + off; off += (size_t)N_P * HID;
    float* oa1 = ws + off; off += (size_t)N_A * HID;
    float* op1 = ws + off; off += (size_t)N_P * HID;
    float* hf  = ws + off; off += (size_t)N_P * 2 * HID;
    int* ccnt  = (int*)(ws + off); off += 3 * NB * 256;
    int* coffs = (int*)(ws + off); off += 3 * NB * 256;
    int* crow  = (int*)(ws + off); off += 3 * 257 + 1;
    int* row   = (int*)(ws + off); off += 3 * 16385 + 1;
    int* ebW  = (int*)(ws + off); off += NE;
    int* ebC  = (int*)(ws + off); off += NE;
    int* ebR  = (int*)(ws + off); off += NE;
    int* esW  = (int*)(ws + off); off += NE;
    int* esC  = (int*)(ws + off); off += NE;
    int* esR  = (int*)(ws + off); off += NE;

    const int* rowW = row;
    const int* rowC = row + 16385;
    const int* rowR = row + 2 * 16385;

    const float* ntA = ntype;            // author scale row (128)
    const float* ntP = ntype + IN_D;     // paper scale row

    // ---- layer job tables (layer 0 reads raw x, scaled by NT on load) ----
    GemmJobs j0{};
    j0.X[0] = x_author; j0.W[0] = W0;                  j0.NT[0] = ntA;
    j0.F[0] = fsW; j0.EL[0] = elw; j0.ER[0] = nullptr; j0.AL[0] = al0;       j0.AR[0] = nullptr;
    j0.X[1] = x_paper;  j0.W[1] = W0;                  j0.NT[1] = ntP;
    j0.F[1] = nullptr; j0.EL[1] = nullptr; j0.ER[1] = erw; j0.AL[1] = nullptr; j0.AR[1] = ar0;
    j0.X[2] = x_paper;  j0.W[2] = W0 + IN_D * HID;     j0.NT[2] = ntP;
    j0.F[2] = fsC; j0.EL[2] = elc; j0.ER[2] = erc;     j0.AL[2] = al0 + 64;  j0.AR[2] = ar0 + 64;
    j0.X[3] = x_paper;  j0.W[3] = W0 + 2 * IN_D * HID; j0.NT[3] = ntP;
    j0.F[3] = fsR; j0.EL[3] = elr; j0.ER[3] = nullptr; j0.AL[3] = al0 + 128; j0.AR[3] = nullptr;
    j0.X[4] = x_author; j0.W[4] = W0 + 2 * IN_D * HID; j0.NT[4] = ntA;
    j0.F[4] = nullptr; j0.EL[4] = nullptr; j0.ER[4] = err; j0.AL[4] = nullptr; j0.AR[4] = ar0 + 128;

    GemmJobs j1{};
    j1.X[0] = oa0; j1.W[0] = W1;                   j1.NT[0] = nullptr;
    j1.F[0] = fsW; j1.EL[0] = elw; j1.ER[0] = nullptr; j1.AL[0] = al1;       j1.AR[0] = nullptr;
    j1.X[1] = op0; j1.W[1] = W1;                   j1.NT[1] = nullptr;
    j1.F[1] = nullptr; j1.EL[1] = nullptr; j1.ER[1] = erw; j1.AL[1] = nullptr; j1.AR[1] = ar1;
    j1.X[2] = op0; j1.W[2] = W1 + HID * HID;       j1.NT[2] = nullptr;
    j1.F[2] = fsC; j1.EL[2] = elc; j1.ER[2] = erc;     j1.AL[2] = al1 + 64;  j1.AR[2] = ar1 + 64;
    j1.X[3] = op0; j1.W[3] = W1 + 2 * HID * HID;   j1.NT[3] = nullptr;
    j1.F[3] = fsR; j1.EL[3] = elr; j1.ER[3] = nullptr; j1.AL[3] = al1 + 128; j1.AR[3] = nullptr;
    j1.X[4] = oa0; j1.W[4] = W1 + 2 * HID * HID;   j1.NT[4] = nullptr;
    j1.F[4] = nullptr; j1.EL[4] = nullptr; j1.ER[4] = err; j1.AL[4] = nullptr; j1.AR[4] = ar1 + 128;

    AggArgs a0{};
    a0.t[0] = {rowW, esW, elw, erw, fsW};
    a0.t[1] = {rowC, esC, elc, erc, fsC};
    a0.t[2] = {rowR, esR, elr, err, fsR};
    a0.b = b0; a0.op = op0; a0.oa = oa0;
    AggArgs a1 = a0;
    a1.b = b1; a1.op = op1; a1.oa = oa1;

    // ---- launches ----
    // CSR build (edge lists constant across layers): two-level partition
    k_chist<<<dim3(NB, 3), 256, 0, stream>>>(dstW, dstC, dstR, ccnt);
    k_coffs<<<1, 768, 0, stream>>>(ccnt, coffs, crow);
    k_cscatter<<<dim3(NB, 3), 256, 0, stream>>>(srcW, dstW, srcC, dstC, srcR, dstR,
                                                coffs, ebW, ebC, ebR);
    k_fine<<<dim3(256, 3), 256, 0, stream>>>(crow, ebW, ebC, ebR, row, esW, esC, esR);

    // layer 0 (ntype scale folded into X load)
    k_gemm<IN_D, 0><<<dim3(N_A / 64, 1, 5), 256, 0, stream>>>(j0);
    k_agg<<<(N_P + N_A) / 4, 256, 0, stream>>>(a0);

    // layer 1 (relu folded into GEMM X loads)
    k_gemm<HID, 1><<<dim3(N_A / 64, 1, 5), 256, 0, stream>>>(j1);
    k_agg<<<(N_P + N_A) / 4, 256, 0, stream>>>(a1);

    // epilogue
    k_hf<<<N_P / 4, 256, 0, stream>>>(op1, hf, ln1gb, attw, attb, ln2gb, fw1, fb1, fw2, fb2);
    k_gemm_out<<<dim3(N_P / 64, (OUTD + 63) / 64), 256, 0, stream>>>(hf, linW, linb, out);
}